// Round 7
// baseline (16316.902 us; speedup 1.0000x reference)
//
#include <hip/hip_runtime.h>

// ResidualParallelWaveGANDiscriminator — fp32 fused WaveNet stack for gfx950.
// Layout: h, skips stored as (Bchunk, C, T), C-major rows of T contiguous floats.
// Workspace-adaptive: batch processed in chunks so 3 big buffers fit ws_size.

#define TT_LEN 32768
#define NB 16
#define NLAYERS 30

__device__ __forceinline__ float lrelu(float x) { return x >= 0.f ? x : 0.2f * x; }

// --- weight pre-transpose: WcT[i][k][c][g] = Wc[i][g][c][k];
//     W2T[i][c][r] = r<64 ? Ws[i][r][c] : Wo[i][r-64][c]
__global__ __launch_bounds__(256) void prep_weights(
    const float* __restrict__ Wc, const float* __restrict__ Wsk,
    const float* __restrict__ Wo, float* __restrict__ WcT, float* __restrict__ W2T)
{
    int idx = blockIdx.x * 256 + threadIdx.x;
    const int nc = NLAYERS * 3 * 64 * 128;          // 737280
    if (idx < nc) {
        int g = idx & 127, c = (idx >> 7) & 63, k = (idx >> 13) % 3, i = idx / 24576;
        WcT[idx] = Wc[((i * 128 + g) * 64 + c) * 3 + k];
    } else {
        int j = idx - nc;                            // 0..245759
        if (j < NLAYERS * 64 * 128) {
            int r = j & 127, c = (j >> 7) & 63, i = j >> 13;
            W2T[j] = (r < 64) ? Wsk[(i * 64 + r) * 64 + c]
                              : Wo[(i * 64 + (r - 64)) * 64 + c];
        }
    }
}

// --- first layer: h[b][o][t] = lrelu(x[b][t]*wf[o] + bf[o])  (b local to chunk)
__global__ __launch_bounds__(256) void first_kernel(
    const float* __restrict__ x, const float* __restrict__ wf,
    const float* __restrict__ bf, float* __restrict__ h)
{
    int t = blockIdx.x * 256 + threadIdx.x;          // 0 .. chunk*TT_LEN
    int b = t >> 15, tt = t & (TT_LEN - 1);
    float xv = x[t];
    #pragma unroll
    for (int o = 0; o < 64; ++o)
        h[((size_t)(b * 64 + o)) * TT_LEN + tt] = lrelu(xv * wf[o] + bf[o]);
}

// --- fused residual layer
// block = 256 thr handles (b, 64-wide t tile): conv(64->128) -> gate -> Ws/Wo GEMM
// thread (tg=tx>>4, tq=tx&15): rows g0=tg*8..+8, cols tloc=tq*4..+4
__global__ __launch_bounds__(256) void layer_kernel(
    const float* __restrict__ hin, float* __restrict__ hout, float* __restrict__ skips,
    const float* __restrict__ WcTl, const float* __restrict__ W2Tl,
    const float* __restrict__ bcl, const float* __restrict__ bsl,
    const float* __restrict__ bol, int d, int init)
{
    // LDS union:
    //  phase1: hT [3][16][64] at 0 (3072) | Wch [3][16][128] at 3072 (6144)  -> 9216
    //  phase2: y [128][68] at 0 (8704) | gate [64][68] at 8704 (4352)        -> 13056
    //  phase3: W2ch [16][128] at 0 (2048) | gate at 8704                     -> 13056
    __shared__ float lds[13056];
    const int tx = threadIdx.x;
    const int b = blockIdx.x >> 9;                   // local batch index in chunk
    const int t0 = (blockIdx.x & 511) * 64;
    const int tg = tx >> 4, tq = tx & 15;
    const int g0 = tg * 8, tloc = tq * 4;

    float acc[8][4];
    #pragma unroll
    for (int i = 0; i < 8; ++i)
        #pragma unroll
        for (int j = 0; j < 4; ++j) acc[i][j] = 0.f;

    // ---- conv: y[g][t] = sum_{c,k} Wc[g][c][k] * h[c][t+(k-1)d]
    for (int c0 = 0; c0 < 64; c0 += 16) {
        __syncthreads();
        #pragma unroll
        for (int n = 0; n < 12; ++n) {               // 3072 h elems
            int idx = n * 256 + tx;
            int j = idx & 63, c = (idx >> 6) & 15, k = idx >> 10;
            int t = t0 + j + (k - 1) * d;
            float v = 0.f;
            if ((unsigned)t < (unsigned)TT_LEN)
                v = hin[((size_t)(b * 64 + c0 + c)) * TT_LEN + t];
            lds[idx] = v;
        }
        #pragma unroll
        for (int n = 0; n < 24; ++n) {               // 6144 W elems
            int idx = n * 256 + tx;
            int g = idx & 127, c = (idx >> 7) & 15, k = idx >> 11;
            lds[3072 + idx] = WcTl[(k * 64 + c0 + c) * 128 + g];
        }
        __syncthreads();
        #pragma unroll 4
        for (int c = 0; c < 16; ++c) {
            #pragma unroll
            for (int k = 0; k < 3; ++k) {
                float4 hv = *(const float4*)&lds[k * 1024 + c * 64 + tloc];
                float4 w0 = *(const float4*)&lds[3072 + k * 2048 + c * 128 + g0];
                float4 w1 = *(const float4*)&lds[3072 + k * 2048 + c * 128 + g0 + 4];
                float wv[8] = {w0.x, w0.y, w0.z, w0.w, w1.x, w1.y, w1.z, w1.w};
                float hvv[4] = {hv.x, hv.y, hv.z, hv.w};
                #pragma unroll
                for (int gj = 0; gj < 8; ++gj)
                    #pragma unroll
                    for (int tj = 0; tj < 4; ++tj)
                        acc[gj][tj] += wv[gj] * hvv[tj];
            }
        }
    }
    __syncthreads();
    // ---- y (+bias) -> LDS, stride 68 to break bank alignment
    #pragma unroll
    for (int gj = 0; gj < 8; ++gj) {
        float bias = bcl[g0 + gj];
        float4 v = make_float4(acc[gj][0] + bias, acc[gj][1] + bias,
                               acc[gj][2] + bias, acc[gj][3] + bias);
        *(float4*)&lds[(g0 + gj) * 68 + tloc] = v;
    }
    __syncthreads();
    // ---- gate[c][t] = tanh(y[c][t]) * sigmoid(y[c+64][t])
    {
        int c = tx >> 2;
        int tb = (tx & 3) * 16;
        #pragma unroll
        for (int j = 0; j < 16; j += 4) {
            float4 a  = *(const float4*)&lds[c * 68 + tb + j];
            float4 bb = *(const float4*)&lds[(c + 64) * 68 + tb + j];
            float4 gv;
            gv.x = tanhf(a.x) / (1.f + expf(-bb.x));
            gv.y = tanhf(a.y) / (1.f + expf(-bb.y));
            gv.z = tanhf(a.z) / (1.f + expf(-bb.z));
            gv.w = tanhf(a.w) / (1.f + expf(-bb.w));
            *(float4*)&lds[8704 + c * 68 + tb + j] = gv;
        }
    }
    // ---- GEMM2: [Ws;Wo](128x64) x gate(64xT)
    float acc2[8][4];
    #pragma unroll
    for (int i = 0; i < 8; ++i)
        #pragma unroll
        for (int j = 0; j < 4; ++j) acc2[i][j] = 0.f;

    for (int c0 = 0; c0 < 64; c0 += 16) {
        __syncthreads();                              // gate writes done / prev FMA done
        #pragma unroll
        for (int n = 0; n < 8; ++n) {                 // 2048 W2 elems
            int idx = n * 256 + tx;
            lds[idx] = W2Tl[c0 * 128 + idx];
        }
        __syncthreads();
        #pragma unroll 4
        for (int c = 0; c < 16; ++c) {
            float4 gvv = *(const float4*)&lds[8704 + (c0 + c) * 68 + tloc];
            float4 w0 = *(const float4*)&lds[c * 128 + g0];
            float4 w1 = *(const float4*)&lds[c * 128 + g0 + 4];
            float wv[8] = {w0.x, w0.y, w0.z, w0.w, w1.x, w1.y, w1.z, w1.w};
            float gvf[4] = {gvv.x, gvv.y, gvv.z, gvv.w};
            #pragma unroll
            for (int gj = 0; gj < 8; ++gj)
                #pragma unroll
                for (int tj = 0; tj < 4; ++tj)
                    acc2[gj][tj] += wv[gj] * gvf[tj];
        }
    }
    // ---- epilogue: rows 0..63 -> skips accumulate; rows 64..127 -> h update
    if (g0 < 64) {
        #pragma unroll
        for (int gj = 0; gj < 8; ++gj) {
            int r = g0 + gj;
            float bsv = bsl[r];
            size_t off = ((size_t)(b * 64 + r)) * TT_LEN + t0 + tloc;
            float4 prev = make_float4(0.f, 0.f, 0.f, 0.f);
            if (!init) prev = *(const float4*)&skips[off];
            float4 o = make_float4(prev.x + acc2[gj][0] + bsv,
                                   prev.y + acc2[gj][1] + bsv,
                                   prev.z + acc2[gj][2] + bsv,
                                   prev.w + acc2[gj][3] + bsv);
            *(float4*)&skips[off] = o;
        }
    } else {
        const float s = 0.70710678118654752f;
        #pragma unroll
        for (int gj = 0; gj < 8; ++gj) {
            int ch = g0 - 64 + gj;
            float bov = bol[ch];
            size_t off = ((size_t)(b * 64 + ch)) * TT_LEN + t0 + tloc;
            float4 hv = *(const float4*)&hin[off];
            float4 o = make_float4((acc2[gj][0] + bov + hv.x) * s,
                                   (acc2[gj][1] + bov + hv.y) * s,
                                   (acc2[gj][2] + bov + hv.z) * s,
                                   (acc2[gj][3] + bov + hv.w) * s);
            *(float4*)&hout[off] = o;
        }
    }
}

// --- final: out = w_l2 . lrelu(w_l1 . lrelu(skips*sc) + b1) + b2
__global__ __launch_bounds__(256) void final_kernel(
    const float* __restrict__ skips, const float* __restrict__ w1,
    const float* __restrict__ b1, const float* __restrict__ w2,
    const float* __restrict__ b2, float* __restrict__ out)
{
    int t = blockIdx.x * 256 + threadIdx.x;          // 0 .. chunk*TT_LEN
    int b = t >> 15, tt = t & (TT_LEN - 1);
    const float sc = 0.18257418583505537f;           // sqrt(1/30)
    float u[64];
    #pragma unroll
    for (int c = 0; c < 64; ++c)
        u[c] = lrelu(skips[((size_t)(b * 64 + c)) * TT_LEN + tt] * sc);
    float o = b2[0];
    #pragma unroll 1
    for (int s = 0; s < 64; ++s) {
        float z = b1[s];
        #pragma unroll
        for (int c = 0; c < 64; ++c) z += w1[s * 64 + c] * u[c];
        o += w2[s] * lrelu(z);
    }
    out[t] = o;
}

extern "C" void kernel_launch(void* const* d_in, const int* in_sizes, int n_in,
                              void* d_out, int out_size, void* d_ws, size_t ws_size,
                              hipStream_t stream)
{
    const float* x   = (const float*)d_in[0];
    const float* wf  = (const float*)d_in[1];
    const float* bf  = (const float*)d_in[2];
    const float* Wc  = (const float*)d_in[3];
    const float* bc  = (const float*)d_in[4];
    const float* Wsk = (const float*)d_in[5];
    const float* bs  = (const float*)d_in[6];
    const float* Wo  = (const float*)d_in[7];
    const float* bo  = (const float*)d_in[8];
    const float* w1  = (const float*)d_in[9];
    const float* b1  = (const float*)d_in[10];
    const float* w2  = (const float*)d_in[11];
    const float* b2  = (const float*)d_in[12];

    float* ws = (float*)d_ws;
    const size_t WF = (size_t)NLAYERS * 24576 + (size_t)NLAYERS * 8192; // 983040 weight floats
    const size_t HSB = (size_t)64 * TT_LEN;          // 2 M floats (8 MB) per batch elem per buffer

    float* WcT  = ws;
    float* W2T  = WcT + (size_t)NLAYERS * 24576;
    float* bufs = ws + WF;

    // Largest power-of-two batch chunk whose 3 buffers fit the workspace.
    size_t avail_f = (ws_size / 4 > WF) ? (ws_size / 4 - WF) : 0;
    int chunk = 16;
    while (chunk > 1 && (size_t)3 * chunk * HSB > avail_f) chunk >>= 1;

    prep_weights<<<3840, 256, 0, stream>>>(Wc, Wsk, Wo, WcT, W2T);

    float* h0 = bufs;
    float* h1 = h0 + (size_t)chunk * HSB;
    float* sk = h1 + (size_t)chunk * HSB;

    for (int b0 = 0; b0 < NB; b0 += chunk) {
        first_kernel<<<chunk * TT_LEN / 256, 256, 0, stream>>>(
            x + (size_t)b0 * TT_LEN, wf, bf, h0);

        float* hin = h0; float* hout = h1;
        for (int i = 0; i < NLAYERS; ++i) {
            int d = 1 << (i % 10);
            layer_kernel<<<chunk * 512, 256, 0, stream>>>(hin, hout, sk,
                WcT + (size_t)i * 24576, W2T + (size_t)i * 8192,
                bc + i * 128, bs + i * 64, bo + i * 64, d, (i == 0) ? 1 : 0);
            float* tmp = hin; hin = hout; hout = tmp;
        }
        final_kernel<<<chunk * TT_LEN / 256, 256, 0, stream>>>(
            sk, w1, b1, w2, b2, (float*)d_out + (size_t)b0 * TT_LEN);
    }
}

// Round 12
// 15735.255 us; speedup vs baseline: 1.0370x; 1.0370x over previous
//
#include <hip/hip_runtime.h>

// ResidualParallelWaveGANDiscriminator — fp32 fused WaveNet stack for gfx950.
// Layout: h, skips stored as (Bchunk, C, T), C-major rows of T contiguous floats.
// Register-gate variant: thread owns rows [4tg,4tg+4) and [64+4tg,+4) so the
// tanh/sigmoid pair is thread-local; no y LDS round-trip; LDS 36864B -> 4 blk/CU.

#define TT_LEN 32768
#define NB 16
#define NLAYERS 30

__device__ __forceinline__ float lrelu(float x) { return x >= 0.f ? x : 0.2f * x; }

// --- weight pre-transpose: WcT[i][k][c][g] = Wc[i][g][c][k];
//     W2T[i][c][r] = r<64 ? Ws[i][r][c] : Wo[i][r-64][c]
__global__ __launch_bounds__(256) void prep_weights(
    const float* __restrict__ Wc, const float* __restrict__ Wsk,
    const float* __restrict__ Wo, float* __restrict__ WcT, float* __restrict__ W2T)
{
    int idx = blockIdx.x * 256 + threadIdx.x;
    const int nc = NLAYERS * 3 * 64 * 128;          // 737280
    if (idx < nc) {
        int g = idx & 127, c = (idx >> 7) & 63, k = (idx >> 13) % 3, i = idx / 24576;
        WcT[idx] = Wc[((i * 128 + g) * 64 + c) * 3 + k];
    } else {
        int j = idx - nc;                            // 0..245759
        if (j < NLAYERS * 64 * 128) {
            int r = j & 127, c = (j >> 7) & 63, i = j >> 13;
            W2T[j] = (r < 64) ? Wsk[(i * 64 + r) * 64 + c]
                              : Wo[(i * 64 + (r - 64)) * 64 + c];
        }
    }
}

// --- first layer: h[b][o][t] = lrelu(x[b][t]*wf[o] + bf[o])  (b local to chunk)
__global__ __launch_bounds__(256) void first_kernel(
    const float* __restrict__ x, const float* __restrict__ wf,
    const float* __restrict__ bf, float* __restrict__ h)
{
    int t = blockIdx.x * 256 + threadIdx.x;
    int b = t >> 15, tt = t & (TT_LEN - 1);
    float xv = x[t];
    #pragma unroll
    for (int o = 0; o < 64; ++o)
        h[((size_t)(b * 64 + o)) * TT_LEN + tt] = lrelu(xv * wf[o] + bf[o]);
}

// --- fused residual layer. Block = 256 thr, one (b, 64-t) tile.
// thread (tg=tx>>4, tq=tx&15): rows {4tg..4tg+3} U {64+4tg..}, cols tloc=4tq..+4
__global__ __launch_bounds__(256) void layer_kernel(
    const float* __restrict__ hin, float* __restrict__ hout, float* __restrict__ skips,
    const float* __restrict__ WcTl, const float* __restrict__ W2Tl,
    const float* __restrict__ bcl, const float* __restrict__ bsl,
    const float* __restrict__ bol, int d, int init)
{
    // LDS union (floats):
    //  conv : hT [3][16][64] @0 (3072) | Wch [3][16][128] @3072 (6144) -> 9216
    //  gemm2: gate [64][68] @0 (4352)  | W2ch [16][128] @4352 (2048)   -> 6400
    __shared__ float lds[9216];                      // 36864 B
    const int tx = threadIdx.x;
    const int b  = blockIdx.x >> 9;
    const int t0 = (blockIdx.x & 511) * 64;
    const int tg = tx >> 4, tq = tx & 15;
    const int ga = tg * 4, tloc = tq * 4;

    float acc[8][4];                                 // [0..3]=xa rows ga+i, [4..7]=xb rows 64+ga+i
    #pragma unroll
    for (int i = 0; i < 8; ++i)
        #pragma unroll
        for (int j = 0; j < 4; ++j) acc[i][j] = 0.f;

    // ---- conv: y[g][t] = sum_{c,k} Wc[g][c][k] * h[c][t+(k-1)d]
    for (int c0 = 0; c0 < 64; c0 += 16) {
        __syncthreads();
        #pragma unroll
        for (int n = 0; n < 12; ++n) {               // 3072 h elems
            int idx = n * 256 + tx;
            int j = idx & 63, c = (idx >> 6) & 15, k = idx >> 10;
            int t = t0 + j + (k - 1) * d;
            float v = 0.f;
            if ((unsigned)t < (unsigned)TT_LEN)
                v = hin[((size_t)(b * 64 + c0 + c)) * TT_LEN + t];
            lds[idx] = v;
        }
        #pragma unroll
        for (int n = 0; n < 24; ++n) {               // 6144 W elems
            int idx = n * 256 + tx;
            int g = idx & 127, c = (idx >> 7) & 15, k = idx >> 11;
            lds[3072 + idx] = WcTl[(k * 64 + c0 + c) * 128 + g];
        }
        __syncthreads();
        #pragma unroll 4
        for (int c = 0; c < 16; ++c) {
            #pragma unroll
            for (int k = 0; k < 3; ++k) {
                float4 hv = *(const float4*)&lds[k * 1024 + c * 64 + tloc];
                float4 wa = *(const float4*)&lds[3072 + k * 2048 + c * 128 + ga];
                float4 wb = *(const float4*)&lds[3072 + k * 2048 + c * 128 + 64 + ga];
                float wva[4] = {wa.x, wa.y, wa.z, wa.w};
                float wvb[4] = {wb.x, wb.y, wb.z, wb.w};
                float hvv[4] = {hv.x, hv.y, hv.z, hv.w};
                #pragma unroll
                for (int i = 0; i < 4; ++i)
                    #pragma unroll
                    for (int j = 0; j < 4; ++j) {
                        acc[i][j]     += wva[i] * hvv[j];
                        acc[4 + i][j] += wvb[i] * hvv[j];
                    }
            }
        }
    }
    __syncthreads();                                 // conv LDS reads done; region reused
    // ---- gate in registers -> lds[0..4352)
    #pragma unroll
    for (int i = 0; i < 4; ++i) {
        float bca = bcl[ga + i], bcb = bcl[64 + ga + i];
        float4 gv;
        float t_[4];
        #pragma unroll
        for (int j = 0; j < 4; ++j) {
            float ya = acc[i][j] + bca;
            float yb = acc[4 + i][j] + bcb;
            t_[j] = tanhf(ya) / (1.f + expf(-yb));
        }
        gv.x = t_[0]; gv.y = t_[1]; gv.z = t_[2]; gv.w = t_[3];
        *(float4*)&lds[(ga + i) * 68 + tloc] = gv;
    }

    // ---- GEMM2: [Ws;Wo](128x64) x gate(64x64)
    float acc2[8][4];
    #pragma unroll
    for (int i = 0; i < 8; ++i)
        #pragma unroll
        for (int j = 0; j < 4; ++j) acc2[i][j] = 0.f;

    for (int c0 = 0; c0 < 64; c0 += 16) {
        __syncthreads();                             // gate writes / prev FMA done
        #pragma unroll
        for (int n = 0; n < 8; ++n) {                // 2048 W2 elems
            int idx = n * 256 + tx;
            lds[4352 + idx] = W2Tl[c0 * 128 + idx];
        }
        __syncthreads();
        #pragma unroll 4
        for (int c = 0; c < 16; ++c) {
            float4 gvv = *(const float4*)&lds[(c0 + c) * 68 + tloc];
            float4 wa = *(const float4*)&lds[4352 + c * 128 + ga];
            float4 wb = *(const float4*)&lds[4352 + c * 128 + 64 + ga];
            float wva[4] = {wa.x, wa.y, wa.z, wa.w};
            float wvb[4] = {wb.x, wb.y, wb.z, wb.w};
            float gvf[4] = {gvv.x, gvv.y, gvv.z, gvv.w};
            #pragma unroll
            for (int i = 0; i < 4; ++i)
                #pragma unroll
                for (int j = 0; j < 4; ++j) {
                    acc2[i][j]     += wva[i] * gvf[j];
                    acc2[4 + i][j] += wvb[i] * gvf[j];
                }
        }
    }
    // ---- epilogue: rows ga+i -> skips (acc2[0..3]) and h (acc2[4..7])
    const float s = 0.70710678118654752f;
    #pragma unroll
    for (int i = 0; i < 4; ++i) {
        int r = ga + i;
        size_t off = ((size_t)(b * 64 + r)) * TT_LEN + t0 + tloc;
        float bsv = bsl[r];
        float4 prev = make_float4(0.f, 0.f, 0.f, 0.f);
        if (!init) prev = *(const float4*)&skips[off];
        float4 o = make_float4(prev.x + acc2[i][0] + bsv,
                               prev.y + acc2[i][1] + bsv,
                               prev.z + acc2[i][2] + bsv,
                               prev.w + acc2[i][3] + bsv);
        *(float4*)&skips[off] = o;

        float bov = bol[r];
        float4 hv = *(const float4*)&hin[off];
        float4 ho = make_float4((acc2[4 + i][0] + bov + hv.x) * s,
                                (acc2[4 + i][1] + bov + hv.y) * s,
                                (acc2[4 + i][2] + bov + hv.z) * s,
                                (acc2[4 + i][3] + bov + hv.w) * s);
        *(float4*)&hout[off] = ho;
    }
}

// --- final: out = w_l2 . lrelu(w_l1 . lrelu(skips*sc) + b1) + b2
__global__ __launch_bounds__(256) void final_kernel(
    const float* __restrict__ skips, const float* __restrict__ w1,
    const float* __restrict__ b1, const float* __restrict__ w2,
    const float* __restrict__ b2, float* __restrict__ out)
{
    int t = blockIdx.x * 256 + threadIdx.x;
    int b = t >> 15, tt = t & (TT_LEN - 1);
    const float sc = 0.18257418583505537f;           // sqrt(1/30)
    float u[64];
    #pragma unroll
    for (int c = 0; c < 64; ++c)
        u[c] = lrelu(skips[((size_t)(b * 64 + c)) * TT_LEN + tt] * sc);
    float o = b2[0];
    #pragma unroll 1
    for (int s = 0; s < 64; ++s) {
        float z = b1[s];
        #pragma unroll
        for (int c = 0; c < 64; ++c) z += w1[s * 64 + c] * u[c];
        o += w2[s] * lrelu(z);
    }
    out[t] = o;
}

extern "C" void kernel_launch(void* const* d_in, const int* in_sizes, int n_in,
                              void* d_out, int out_size, void* d_ws, size_t ws_size,
                              hipStream_t stream)
{
    const float* x   = (const float*)d_in[0];
    const float* wf  = (const float*)d_in[1];
    const float* bf  = (const float*)d_in[2];
    const float* Wc  = (const float*)d_in[3];
    const float* bc  = (const float*)d_in[4];
    const float* Wsk = (const float*)d_in[5];
    const float* bs  = (const float*)d_in[6];
    const float* Wo  = (const float*)d_in[7];
    const float* bo  = (const float*)d_in[8];
    const float* w1  = (const float*)d_in[9];
    const float* b1  = (const float*)d_in[10];
    const float* w2  = (const float*)d_in[11];
    const float* b2  = (const float*)d_in[12];

    float* ws = (float*)d_ws;
    const size_t WF = (size_t)NLAYERS * 24576 + (size_t)NLAYERS * 8192; // 983040 floats
    const size_t HSB = (size_t)64 * TT_LEN;          // 2M floats per batch elem per buffer

    float* WcT  = ws;
    float* W2T  = WcT + (size_t)NLAYERS * 24576;
    float* bufs = ws + WF;

    size_t avail_f = (ws_size / 4 > WF) ? (ws_size / 4 - WF) : 0;
    int chunk = 16;
    while (chunk > 1 && (size_t)3 * chunk * HSB > avail_f) chunk >>= 1;

    prep_weights<<<3840, 256, 0, stream>>>(Wc, Wsk, Wo, WcT, W2T);

    float* h0 = bufs;
    float* h1 = h0 + (size_t)chunk * HSB;
    float* sk = h1 + (size_t)chunk * HSB;

    for (int b0 = 0; b0 < NB; b0 += chunk) {
        first_kernel<<<chunk * TT_LEN / 256, 256, 0, stream>>>(
            x + (size_t)b0 * TT_LEN, wf, bf, h0);

        float* hin = h0; float* hout = h1;
        for (int i = 0; i < NLAYERS; ++i) {
            int d = 1 << (i % 10);
            layer_kernel<<<chunk * 512, 256, 0, stream>>>(hin, hout, sk,
                WcT + (size_t)i * 24576, W2T + (size_t)i * 8192,
                bc + i * 128, bs + i * 64, bo + i * 64, d, (i == 0) ? 1 : 0);
            float* tmp = hin; hin = hout; hout = tmp;
        }
        final_kernel<<<chunk * TT_LEN / 256, 256, 0, stream>>>(
            sk, w1, b1, w2, b2, (float*)d_out + (size_t)b0 * TT_LEN);
    }
}